// Round 1
// baseline (44.543 us; speedup 1.0000x reference)
//
#include <hip/hip_runtime.h>

// Problem constants (from reference): B=8, T=4096, LZ=1024, D=1024
#define B_N   8
#define T_N   4096
#define LZ_N  1024
#define D_N   1024

// ---------------------------------------------------------------------------
// Kernel 1: per-batch exclusive prefix sum of b (0/1 ints), clipped to
// [0, LZ-1].  One block per batch, 256 threads, 16 elements/thread.
// ---------------------------------------------------------------------------
__global__ __launch_bounds__(256) void scan_kernel(const int* __restrict__ b,
                                                   int* __restrict__ idx) {
    const int batch = blockIdx.x;
    const int tid   = threadIdx.x;           // 0..255
    const int* bb = b   + (size_t)batch * T_N;
    int*       ii = idx + (size_t)batch * T_N;

    // Load 16 contiguous ints per thread (4 x int4).
    int vals[16];
    const int4* b4 = (const int4*)(bb + tid * 16);
#pragma unroll
    for (int j = 0; j < 4; ++j) {
        int4 v = b4[j];
        vals[4 * j + 0] = v.x;
        vals[4 * j + 1] = v.y;
        vals[4 * j + 2] = v.z;
        vals[4 * j + 3] = v.w;
    }

    int local_sum = 0;
#pragma unroll
    for (int j = 0; j < 16; ++j) local_sum += vals[j];

    // Block-level inclusive scan of the 256 per-thread sums (Hillis-Steele).
    __shared__ int sh[256];
    sh[tid] = local_sum;
    __syncthreads();
#pragma unroll
    for (int off = 1; off < 256; off <<= 1) {
        int v = (tid >= off) ? sh[tid - off] : 0;
        __syncthreads();
        sh[tid] += v;
        __syncthreads();
    }
    int excl = (tid == 0) ? 0 : sh[tid - 1];

    // Emit clipped exclusive prefix for each owned element.
    int run = excl;
#pragma unroll
    for (int j = 0; j < 16; ++j) {
        int v = run;                 // exclusive prefix sum at this position
        run += vals[j];
        v = v < 0 ? 0 : (v > (LZ_N - 1) ? (LZ_N - 1) : v);
        ii[tid * 16 + j] = v;
    }
}

// ---------------------------------------------------------------------------
// Kernel 2: one block per (batch, t) output row.  256 threads x float4 = 1024
// floats.  out[row] = p*z[idx[t]] + (1-p)*z[idx[t-1]]   (t>0)
//           out[row] = z[idx[0]]                         (t==0)
// ---------------------------------------------------------------------------
__global__ __launch_bounds__(256) void smooth_kernel(const float* __restrict__ z,
                                                     const float* __restrict__ p,
                                                     const int* __restrict__ idx,
                                                     float* __restrict__ out) {
    const int row   = blockIdx.x;            // 0 .. B*T-1
    const int batch = row >> 12;             // T = 4096
    const int t     = row & (T_N - 1);
    const int tid   = threadIdx.x;

    const int i0 = idx[row];
    const float4* zr0 = (const float4*)(z + ((size_t)batch * LZ_N + i0) * D_N);
    float4 v0 = zr0[tid];

    float4 r;
    if (t == 0) {
        r = v0;
    } else {
        const int   i1 = idx[row - 1];
        const float c  = p[row];
        const float om = 1.0f - c;
        const float4* zr1 = (const float4*)(z + ((size_t)batch * LZ_N + i1) * D_N);
        float4 v1 = zr1[tid];
        r.x = c * v0.x + om * v1.x;
        r.y = c * v0.y + om * v1.y;
        r.z = c * v0.z + om * v1.z;
        r.w = c * v0.w + om * v1.w;
    }

    ((float4*)out)[(size_t)row * (D_N / 4) + tid] = r;
}

// ---------------------------------------------------------------------------
extern "C" void kernel_launch(void* const* d_in, const int* in_sizes, int n_in,
                              void* d_out, int out_size, void* d_ws, size_t ws_size,
                              hipStream_t stream) {
    const float* z = (const float*)d_in[0];   // (B, LZ, D) f32
    const float* p = (const float*)d_in[1];   // (B, T)     f32
    const int*   b = (const int*)d_in[2];     // (B, T)     i32
    // d_in[3] = original_len (unused; == T)

    float* out = (float*)d_out;               // (B, T, D) f32
    int*   idx = (int*)d_ws;                  // B*T ints = 128 KB scratch

    scan_kernel<<<B_N, 256, 0, stream>>>(b, idx);
    smooth_kernel<<<B_N * T_N, 256, 0, stream>>>(z, p, idx, out);
}

// Round 3
// 36.065 us; speedup vs baseline: 1.2351x; 1.2351x over previous
//
#include <hip/hip_runtime.h>

// Problem constants (from reference): B=8, T=4096, LZ=1024, D=1024
#define B_N   8
#define T_N   4096
#define LZ_N  1024
#define D_N   1024
#define ROWS_TOTAL (B_N * T_N)            // 32768
#define NBLK  2048                        // blocks for smooth kernel (divisible by 8)
#define ROWS_PER_BLK (ROWS_TOTAL / NBLK)  // 16 contiguous rows per block

typedef float fx4 __attribute__((ext_vector_type(4)));   // clang vector: OK for nontemporal builtins

// ---------------------------------------------------------------------------
// Kernel 1: per-batch exclusive prefix sum of b (0/1 ints), clipped to
// [0, LZ-1].  One block per batch, 256 threads, 16 elements/thread.
// ---------------------------------------------------------------------------
__global__ __launch_bounds__(256) void scan_kernel(const int* __restrict__ b,
                                                   int* __restrict__ idx) {
    const int batch = blockIdx.x;
    const int tid   = threadIdx.x;           // 0..255
    const int* bb = b   + (size_t)batch * T_N;
    int*       ii = idx + (size_t)batch * T_N;

    // Load 16 contiguous ints per thread (4 x int4).
    int vals[16];
    const int4* b4 = (const int4*)(bb + tid * 16);
#pragma unroll
    for (int j = 0; j < 4; ++j) {
        int4 v = b4[j];
        vals[4 * j + 0] = v.x;
        vals[4 * j + 1] = v.y;
        vals[4 * j + 2] = v.z;
        vals[4 * j + 3] = v.w;
    }

    int local_sum = 0;
#pragma unroll
    for (int j = 0; j < 16; ++j) local_sum += vals[j];

    // Block-level inclusive scan of the 256 per-thread sums (Hillis-Steele).
    __shared__ int sh[256];
    sh[tid] = local_sum;
    __syncthreads();
#pragma unroll
    for (int off = 1; off < 256; off <<= 1) {
        int v = (tid >= off) ? sh[tid - off] : 0;
        __syncthreads();
        sh[tid] += v;
        __syncthreads();
    }
    int excl = (tid == 0) ? 0 : sh[tid - 1];

    // Emit clipped exclusive prefix for each owned element.
    int run = excl;
#pragma unroll
    for (int j = 0; j < 16; ++j) {
        int v = run;                 // exclusive prefix sum at this position
        run += vals[j];
        v = v < 0 ? 0 : (v > (LZ_N - 1) ? (LZ_N - 1) : v);
        ii[tid * 16 + j] = v;
    }
}

// ---------------------------------------------------------------------------
// Kernel 2: each block processes ROWS_PER_BLK (=16) CONTIGUOUS output rows.
//  - thread's column is fixed (tid-th float4 of the row), so z[idx[t-1]] is
//    carried in registers from the previous iteration; z is re-loaded only
//    when idx changes (block-uniform branch, no divergence).
//  - XCD-bijective swizzle: blocks resident on one XCD cover exactly one
//    batch -> z working set per XCD = 4 MB = its private L2.
//  - nontemporal stores: out is write-once, keep it out of L2.
// ---------------------------------------------------------------------------
__global__ __launch_bounds__(256) void smooth_kernel(const float* __restrict__ z,
                                                     const float* __restrict__ p,
                                                     const int* __restrict__ idx,
                                                     float* __restrict__ out) {
    const int bid  = blockIdx.x;
    // round-robin XCD dispatch assumed: bid%8 = XCD. Give XCD k the
    // contiguous swz-range [k*256, (k+1)*256) -> rows [k*4096,(k+1)*4096)
    // = exactly batch k.
    const int swz  = (bid & 7) * (NBLK / 8) + (bid >> 3);
    const int base = swz * ROWS_PER_BLK;          // first row of this chunk
    const int batch = base >> 12;                 // T_N = 4096
    const int tid  = threadIdx.x;

    const float* zb = z + (size_t)batch * LZ_N * D_N;

    const int t0 = base & (T_N - 1);
    int i_prev = (t0 == 0) ? idx[base] : idx[base - 1];
    fx4 v_prev = ((const fx4*)(zb + (size_t)i_prev * D_N))[tid];

    fx4* outp = (fx4*)out + (size_t)base * (D_N / 4) + tid;

#pragma unroll 4
    for (int j = 0; j < ROWS_PER_BLK; ++j) {
        const int row = base + j;
        const int i0  = idx[row];
        fx4 v0;
        if (i0 != i_prev) {                       // block-uniform condition
            v0 = ((const fx4*)(zb + (size_t)i0 * D_N))[tid];
        } else {
            v0 = v_prev;
        }
        // t==0: out = z[idx[0]] exactly -> force c=1 (om*v_prev == 0, finite)
        const float c  = ((row & (T_N - 1)) == 0) ? 1.0f : p[row];
        const float om = 1.0f - c;
        fx4 r = c * v0 + om * v_prev;
        __builtin_nontemporal_store(r, outp + (size_t)j * (D_N / 4));
        i_prev = i0;
        v_prev = v0;
    }
}

// ---------------------------------------------------------------------------
extern "C" void kernel_launch(void* const* d_in, const int* in_sizes, int n_in,
                              void* d_out, int out_size, void* d_ws, size_t ws_size,
                              hipStream_t stream) {
    const float* z = (const float*)d_in[0];   // (B, LZ, D) f32
    const float* p = (const float*)d_in[1];   // (B, T)     f32
    const int*   b = (const int*)d_in[2];     // (B, T)     i32
    // d_in[3] = original_len (unused; == T)

    float* out = (float*)d_out;               // (B, T, D) f32
    int*   idx = (int*)d_ws;                  // B*T ints = 128 KB scratch

    scan_kernel<<<B_N, 256, 0, stream>>>(b, idx);
    smooth_kernel<<<NBLK, 256, 0, stream>>>(z, p, idx, out);
}

// Round 4
// 32.933 us; speedup vs baseline: 1.3525x; 1.0951x over previous
//
#include <hip/hip_runtime.h>

// Problem constants (from reference): B=8, T=4096, LZ=1024, D=1024
#define B_N   8
#define T_N   4096
#define LZ_N  1024
#define D_N   1024
#define ROWS_TOTAL (B_N * T_N)            // 32768
#define NBLK  2048                        // blocks (divisible by 8 for XCD swizzle)
#define ROWS_PER_BLK (ROWS_TOTAL / NBLK)  // 16 contiguous rows per block

typedef float fx4 __attribute__((ext_vector_type(4)));

// ---------------------------------------------------------------------------
// Fused kernel: each block handles 16 contiguous output rows [base, base+16).
// Preamble: block recomputes the exclusive cumsum of b[batch][0..base+16)
//   itself (<=16 ints/thread, wave-shfl scan) and stashes the 17 needed
//   clipped idx values + 16 p coefs in LDS. b is 16KB/batch -> L2-resident,
//   so redundant re-reads are L2 traffic, not HBM.
// Main loop: thread's column fixed (tid-th float4); z row re-loaded only when
//   idx changes (block-uniform branch); out written with nontemporal stores.
// XCD-bijective swizzle: each XCD covers exactly one batch -> z working set
//   per XCD = 4MB = its private L2.
// ---------------------------------------------------------------------------
__global__ __launch_bounds__(256) void fused_kernel(const float* __restrict__ z,
                                                    const float* __restrict__ p,
                                                    const int* __restrict__ b,
                                                    float* __restrict__ out) {
    const int bid   = blockIdx.x;
    const int swz   = (bid & 7) * (NBLK / 8) + (bid >> 3);
    const int base  = swz * ROWS_PER_BLK;         // first row of this chunk
    const int batch = base >> 12;                 // T_N = 4096
    const int t0    = base & (T_N - 1);
    const int tid   = threadIdx.x;
    const int lane  = tid & 63;
    const int wid   = tid >> 6;
    const int last_chunk = t0 >> 4;               // chunk index containing base
    const int nchunk     = last_chunk + 1;        // chunks covering [0, base+16)

    const int* bb = b + (size_t)batch * T_N;

    // --- per-thread chunk load + sum (only threads < nchunk do real work) ---
    int vals[16];
    int lsum = 0;
    if (tid < nchunk) {
        const int4* b4 = (const int4*)(bb + tid * 16);
#pragma unroll
        for (int j = 0; j < 4; ++j) {
            int4 v = b4[j];
            vals[4 * j + 0] = v.x;
            vals[4 * j + 1] = v.y;
            vals[4 * j + 2] = v.z;
            vals[4 * j + 3] = v.w;
        }
#pragma unroll
        for (int j = 0; j < 16; ++j) lsum += vals[j];
    }

    // --- inclusive scan over the 256 per-thread sums: shfl within wave, then
    //     combine the 4 wave totals once through LDS ---
    int s = lsum;
#pragma unroll
    for (int off = 1; off < 64; off <<= 1) {
        int n = __shfl_up(s, off, 64);
        if (lane >= off) s += n;
    }
    __shared__ int   wsum[4];
    __shared__ int   sh_idx[17];
    __shared__ float sh_p[16];
    if (lane == 63) wsum[wid] = s;
    __syncthreads();
    int wbase = 0;
#pragma unroll
    for (int w = 0; w < 3; ++w) if (w < wid) wbase += wsum[w];
    const int incl  = s + wbase;    // inclusive cumsum of chunk sums through tid
    const int exclc = incl - lsum;  // exclusive cumsum at this chunk's start

    // --- owner thread emits idx[base..base+15]; neighbor emits idx[base-1] ---
    if (tid == last_chunk) {
        int run = exclc;
        int first = -1;
#pragma unroll
        for (int j = 0; j < 16; ++j) {
            int v = run;
            run += vals[j];
            v = v > (LZ_N - 1) ? (LZ_N - 1) : v;
            if (j == 0) first = v;
            sh_idx[1 + j] = v;
        }
        if (t0 == 0) sh_idx[0] = first;   // row 0: prev value unused (c=1)
    }
    if (t0 > 0 && tid == last_chunk - 1) {
        int v = incl - vals[15];          // excl cumsum at base-1
        v = v > (LZ_N - 1) ? (LZ_N - 1) : v;
        sh_idx[0] = v;
    }
    if (tid < ROWS_PER_BLK) {
        const int row = base + tid;
        sh_p[tid] = ((row & (T_N - 1)) == 0) ? 1.0f : p[row];
    }
    __syncthreads();

    // --- gather + smooth + nontemporal store ---
    const float* zb = z + (size_t)batch * LZ_N * D_N;
    int i_prev = sh_idx[0];
    fx4 v_prev = ((const fx4*)(zb + (size_t)i_prev * D_N))[tid];

    fx4* outp = (fx4*)out + (size_t)base * (D_N / 4) + tid;

#pragma unroll 4
    for (int j = 0; j < ROWS_PER_BLK; ++j) {
        const int i0 = sh_idx[j + 1];
        fx4 v0;
        if (i0 != i_prev) {                       // block-uniform condition
            v0 = ((const fx4*)(zb + (size_t)i0 * D_N))[tid];
        } else {
            v0 = v_prev;
        }
        const float c  = sh_p[j];
        const float om = 1.0f - c;
        fx4 r = c * v0 + om * v_prev;
        __builtin_nontemporal_store(r, outp + (size_t)j * (D_N / 4));
        i_prev = i0;
        v_prev = v0;
    }
}

// ---------------------------------------------------------------------------
extern "C" void kernel_launch(void* const* d_in, const int* in_sizes, int n_in,
                              void* d_out, int out_size, void* d_ws, size_t ws_size,
                              hipStream_t stream) {
    const float* z = (const float*)d_in[0];   // (B, LZ, D) f32
    const float* p = (const float*)d_in[1];   // (B, T)     f32
    const int*   b = (const int*)d_in[2];     // (B, T)     i32
    // d_in[3] = original_len (unused; == T)

    float* out = (float*)d_out;               // (B, T, D) f32

    fused_kernel<<<NBLK, 256, 0, stream>>>(z, p, b, out);
}

// Round 5
// 31.145 us; speedup vs baseline: 1.4302x; 1.0574x over previous
//
#include <hip/hip_runtime.h>

// Problem constants (from reference): B=8, T=4096, LZ=1024, D=1024
#define B_N   8
#define T_N   4096
#define LZ_N  1024
#define D_N   1024
#define ROWS_TOTAL (B_N * T_N)            // 32768
#define NBLK  2048                        // blocks (divisible by 8 for XCD swizzle)
#define ROWS_PER_BLK (ROWS_TOTAL / NBLK)  // 16 contiguous rows per block

typedef float fx4 __attribute__((ext_vector_type(4)));

// ---------------------------------------------------------------------------
// Fused kernel: each block handles 16 contiguous output rows [base, base+16).
// Preamble: block recomputes the exclusive cumsum of b[batch][0..base+16)
//   itself (<=16 ints/thread, wave-shfl scan) and stashes the 17 needed
//   clipped idx values + 16 p coefs in LDS. b is 16KB/batch -> L2-resident.
// Main loop: BRANCH-FREE — one unconditional z load per row (addresses all
//   known after the preamble), so 16 independent loads pipeline freely;
//   repeats of the same z row are L1 hits. v_prev carried in registers.
// XCD-bijective swizzle: each XCD covers exactly one batch -> z working set
//   per XCD = 4MB = its private L2.  Nontemporal stores keep the write-once
//   output stream from evicting z.
// ---------------------------------------------------------------------------
__global__ __launch_bounds__(256) void fused_kernel(const float* __restrict__ z,
                                                    const float* __restrict__ p,
                                                    const int* __restrict__ b,
                                                    float* __restrict__ out) {
    const int bid   = blockIdx.x;
    const int swz   = (bid & 7) * (NBLK / 8) + (bid >> 3);
    const int base  = swz * ROWS_PER_BLK;         // first row of this chunk
    const int batch = base >> 12;                 // T_N = 4096
    const int t0    = base & (T_N - 1);
    const int tid   = threadIdx.x;
    const int lane  = tid & 63;
    const int wid   = tid >> 6;
    const int last_chunk = t0 >> 4;               // chunk index containing base
    const int nchunk     = last_chunk + 1;        // chunks covering [0, base+16)

    const int* bb = b + (size_t)batch * T_N;

    // --- per-thread chunk load + sum (only threads < nchunk do real work) ---
    int vals[16];
    int lsum = 0;
    if (tid < nchunk) {
        const int4* b4 = (const int4*)(bb + tid * 16);
#pragma unroll
        for (int j = 0; j < 4; ++j) {
            int4 v = b4[j];
            vals[4 * j + 0] = v.x;
            vals[4 * j + 1] = v.y;
            vals[4 * j + 2] = v.z;
            vals[4 * j + 3] = v.w;
        }
#pragma unroll
        for (int j = 0; j < 16; ++j) lsum += vals[j];
    }

    // --- inclusive scan over the 256 per-thread sums: shfl within wave, then
    //     combine the 4 wave totals once through LDS ---
    int s = lsum;
#pragma unroll
    for (int off = 1; off < 64; off <<= 1) {
        int n = __shfl_up(s, off, 64);
        if (lane >= off) s += n;
    }
    __shared__ int   wsum[4];
    __shared__ int   sh_idx[17];
    __shared__ float sh_p[16];
    if (lane == 63) wsum[wid] = s;
    __syncthreads();
    int wbase = 0;
#pragma unroll
    for (int w = 0; w < 3; ++w) if (w < wid) wbase += wsum[w];
    const int incl  = s + wbase;    // inclusive cumsum of chunk sums through tid
    const int exclc = incl - lsum;  // exclusive cumsum at this chunk's start

    // --- owner thread emits idx[base..base+15]; neighbor emits idx[base-1] ---
    if (tid == last_chunk) {
        int run = exclc;
        int first = -1;
#pragma unroll
        for (int j = 0; j < 16; ++j) {
            int v = run;
            run += vals[j];
            v = v > (LZ_N - 1) ? (LZ_N - 1) : v;
            if (j == 0) first = v;
            sh_idx[1 + j] = v;
        }
        if (t0 == 0) sh_idx[0] = first;   // row 0: prev value unused (c=1)
    }
    if (t0 > 0 && tid == last_chunk - 1) {
        int v = incl - vals[15];          // excl cumsum at base-1
        v = v > (LZ_N - 1) ? (LZ_N - 1) : v;
        sh_idx[0] = v;
    }
    if (tid < ROWS_PER_BLK) {
        const int row = base + tid;
        sh_p[tid] = ((row & (T_N - 1)) == 0) ? 1.0f : p[row];
    }
    __syncthreads();

    // --- gather + smooth + nontemporal store: branch-free main loop ---
    const float* zb = z + (size_t)batch * LZ_N * D_N;
    fx4 v_prev = ((const fx4*)(zb + (size_t)sh_idx[0] * D_N))[tid];

    fx4* outp = (fx4*)out + (size_t)base * (D_N / 4) + tid;

#pragma unroll
    for (int j = 0; j < ROWS_PER_BLK; ++j) {
        // unconditional load: repeated rows hit L1 (same 4KB line set just
        // fetched); addresses are all known -> loads pipeline independently.
        fx4 v0 = ((const fx4*)(zb + (size_t)sh_idx[j + 1] * D_N))[tid];
        const float c  = sh_p[j];
        const float om = 1.0f - c;
        fx4 r = c * v0 + om * v_prev;
        __builtin_nontemporal_store(r, outp + (size_t)j * (D_N / 4));
        v_prev = v0;
    }
}

// ---------------------------------------------------------------------------
extern "C" void kernel_launch(void* const* d_in, const int* in_sizes, int n_in,
                              void* d_out, int out_size, void* d_ws, size_t ws_size,
                              hipStream_t stream) {
    const float* z = (const float*)d_in[0];   // (B, LZ, D) f32
    const float* p = (const float*)d_in[1];   // (B, T)     f32
    const int*   b = (const int*)d_in[2];     // (B, T)     i32
    // d_in[3] = original_len (unused; == T)

    float* out = (float*)d_out;               // (B, T, D) f32

    fused_kernel<<<NBLK, 256, 0, stream>>>(z, p, b, out);
}